// Round 16
// baseline (105.049 us; speedup 1.0000x reference)
//
#include <hip/hip_runtime.h>

#define NN 8192
#define FIN 256
#define FOUT 128
#define BKJ 128            /* j per step */
#define JSPLIT 4
#define LALPHA 0.2f
#define LOG2E 1.4426950408889634f

typedef short bf16x8 __attribute__((ext_vector_type(8)));
typedef float f32x4 __attribute__((ext_vector_type(4)));

#define FOR8(X) X(0) X(1) X(2) X(3) X(4) X(5) X(6) X(7)

static __device__ __forceinline__ unsigned short f2bf(float f) {
    unsigned u = __float_as_uint(f);
    u += 0x7FFFu + ((u >> 16) & 1u);   // RNE
    return (unsigned short)(u >> 16);
}
static __device__ __forceinline__ float ex2(float x) {
    float r; asm("v_exp_f32 %0, %1" : "=v"(r) : "v"(x)); return r;
}

// ---------------- K1: Wh = h@W (f32), si = Wh@a1, sj = Wh@a2, WhT bf16 ----------------
__global__ __launch_bounds__(256) void gat_k1(
    const float* __restrict__ h, const float* __restrict__ W,
    const float* __restrict__ a, unsigned short* __restrict__ WhT,
    float* __restrict__ si, float* __restrict__ sj)
{
    __shared__ float Wt[64 * 128];          // 32 KB: W chunk [64k][128c]
    __shared__ float hT[64 * 36 + 4];       // 9 KB: h chunk transposed [64k][32r] pad 36
    const int t = threadIdx.x;
    const int r0 = blockIdx.x * 32;
    const int rg = t >> 5;    // rows rg*4..+4
    const int cg = t & 31;    // cols cg*4..+4
    float acc[4][4] = {{0.f,0.f,0.f,0.f},{0.f,0.f,0.f,0.f},{0.f,0.f,0.f,0.f},{0.f,0.f,0.f,0.f}};

    for (int kc = 0; kc < 4; ++kc) {
        __syncthreads();
        const float4* Ws = (const float4*)(W + kc * 64 * FOUT);
        float4* Wd = (float4*)Wt;
        #pragma unroll
        for (int v = 0; v < 8; ++v) Wd[v * 256 + t] = Ws[v * 256 + t];
        {
            const int hr = t >> 3, hk = (t & 7) * 8;
            const float* hs = h + (size_t)(r0 + hr) * FIN + kc * 64 + hk;
            float4 x0 = *(const float4*)hs;
            float4 x1 = *(const float4*)(hs + 4);
            hT[(hk + 0) * 36 + hr] = x0.x; hT[(hk + 1) * 36 + hr] = x0.y;
            hT[(hk + 2) * 36 + hr] = x0.z; hT[(hk + 3) * 36 + hr] = x0.w;
            hT[(hk + 4) * 36 + hr] = x1.x; hT[(hk + 5) * 36 + hr] = x1.y;
            hT[(hk + 6) * 36 + hr] = x1.z; hT[(hk + 7) * 36 + hr] = x1.w;
        }
        __syncthreads();
        #pragma unroll 8
        for (int kk = 0; kk < 64; ++kk) {
            float4 hv4 = *(const float4*)&hT[kk * 36 + rg * 4];
            float4 wv4 = *(const float4*)&Wt[kk * 128 + cg * 4];
            float hv[4] = {hv4.x, hv4.y, hv4.z, hv4.w};
            float wv[4] = {wv4.x, wv4.y, wv4.z, wv4.w};
            #pragma unroll
            for (int rr = 0; rr < 4; ++rr)
                #pragma unroll
                for (int cc = 0; cc < 4; ++cc)
                    acc[rr][cc] = fmaf(hv[rr], wv[cc], acc[rr][cc]);
        }
    }
    float4 a1v4 = *(const float4*)(a + cg * 4);
    float4 a2v4 = *(const float4*)(a + FOUT + cg * 4);
    float a1v[4] = {a1v4.x, a1v4.y, a1v4.z, a1v4.w};
    float a2v[4] = {a2v4.x, a2v4.y, a2v4.z, a2v4.w};
    float ps[4], qs[4];
    #pragma unroll
    for (int rr = 0; rr < 4; ++rr) {
        float p = 0.f, q = 0.f;
        #pragma unroll
        for (int cc = 0; cc < 4; ++cc) {
            p = fmaf(acc[rr][cc], a1v[cc], p);
            q = fmaf(acc[rr][cc], a2v[cc], q);
        }
        ps[rr] = p; qs[rr] = q;
    }
    #pragma unroll
    for (int off = 1; off <= 16; off <<= 1) {
        #pragma unroll
        for (int rr = 0; rr < 4; ++rr) {
            ps[rr] += __shfl_xor(ps[rr], off);
            qs[rr] += __shfl_xor(qs[rr], off);
        }
    }
    if (cg == 0) {
        #pragma unroll
        for (int rr = 0; rr < 4; ++rr) {
            si[r0 + rg * 4 + rr] = ps[rr];
            sj[r0 + rg * 4 + rr] = qs[rr];
        }
    }
    #pragma unroll
    for (int cc = 0; cc < 4; ++cc) {
        ushort4 v;
        v.x = f2bf(acc[0][cc]); v.y = f2bf(acc[1][cc]);
        v.z = f2bf(acc[2][cc]); v.w = f2bf(acc[3][cc]);
        *(ushort4*)(WhT + (size_t)(cg * 4 + cc) * NN + r0 + rg * 4) = v;
    }
}

// ---------------- K1v: sjmax = max_j sj; vpk[j]=bf16(e^{sj-sjmax}); zpk[j]=bf16(e^{0.2(sj-sjmax)}) ----------------
__global__ __launch_bounds__(256) void gat_k1v(
    const float* __restrict__ sj, float* __restrict__ sjmax,
    unsigned short* __restrict__ vpk, unsigned short* __restrict__ zpk)
{
    __shared__ float red[256];
    float m = -1e30f;
    for (int i = threadIdx.x; i < NN; i += 256) m = fmaxf(m, sj[i]);
    red[threadIdx.x] = m;
    __syncthreads();
    for (int o = 128; o > 0; o >>= 1) {
        if (threadIdx.x < o) red[threadIdx.x] = fmaxf(red[threadIdx.x], red[threadIdx.x + o]);
        __syncthreads();
    }
    if (threadIdx.x == 0) sjmax[0] = red[0];
    __syncthreads();
    const float mx = red[0];
    for (int i = threadIdx.x; i < NN; i += 256) {
        float d = sj[i] - mx;
        vpk[i] = f2bf(ex2(d * LOG2E));
        zpk[i] = f2bf(ex2(LALPHA * d * LOG2E));
    }
}

// ---------------- K2: regime-factorized masked softmax (no exp in loop) + 2x P@Wh via MFMA ----------------
// P[i,j] = adj * ( [si+sj>0] u_i v_j  +  [si+sj<=0] w_i z_j ),  m_i = leaky(si+sjmax)
// u=e^{xm-m}, w=e^{0.2xm-m}; test [si+sj>0] <=> v_j > e^{-xm} (monotone; boundary-continuous).
template<int JS, bool FINAL>
__global__ __launch_bounds__(256, 2) void gat_k2(
    const int* __restrict__ adj, const unsigned short* __restrict__ WhT,
    const float* __restrict__ si, const unsigned short* __restrict__ vpk,
    const unsigned short* __restrict__ zpk, const float* __restrict__ sjmaxp,
    float* __restrict__ lsum, float* __restrict__ Opart, float* __restrict__ out)
{
    const int JR_ = NN / JS;
    const int NST_ = JR_ / BKJ;
    __shared__ __align__(16) unsigned short tile[2][16384];   // 2 x 32 KB WhT tile, XOR-swizzled
    __shared__ __align__(16) unsigned short vpk_lds[NN / JS];
    __shared__ __align__(16) unsigned short zpk_lds[NN / JS];
    const int t = threadIdx.x;
    const int w = t >> 6, l = t & 63;
    const int rb = (int)blockIdx.x / JS, js = (int)blockIdx.x % JS;
    const int iw = rb * 64 + w * 16;       // wave's 16 rows
    const int j0 = js * JR_;
    const int row = l & 15, kg = l >> 4;   // A-frag: row=l&15, k-slice=kg*8..+8
    const int kg8 = kg * 8;

    const float si_l = si[iw + row];
    const float sjmax = sjmaxp[0];
    const float xm = si_l + sjmax;
    const float m_row = fmaxf(xm, LALPHA * xm);
    const float thr = ex2(-xm * LOG2E);               // e^{-xm}
    const float uu = ex2((xm - m_row) * LOG2E);       // e^{xm-m}
    const float ww = ex2((LALPHA * xm - m_row) * LOG2E);
    const int* adjb = adj + (size_t)(iw + row) * NN + j0 + kg8;

    // prologue: vpk/zpk slices -> LDS (coalesced 16B)
    for (int i = t * 8; i < JR_; i += 2048) {
        *(int4*)&vpk_lds[i] = *(const int4*)(vpk + j0 + i);
        *(int4*)&zpk_lds[i] = *(const int4*)(zpk + j0 + i);
    }

    // staging: lane t covers WhT col c=v*16+(t>>4), 16B j-chunk ch=t&15; swz = (c&7)<<4
#define GSRC_D(v) const unsigned short* gsrc##v = WhT + (size_t)(v * 16 + (t >> 4)) * NN + j0 + (t & 15) * 8; \
                  const int ldo##v = ((v * 256 + t) * 16) ^ (((t >> 4) & 7) << 4);
    FOR8(GSRC_D)

#define REG_D(v) int4 stg##v, adr##v;
    FOR8(REG_D)
#define STG_L0(v) stg##v = *(const int4*)(gsrc##v);
    FOR8(STG_L0)
#define ADR_L0(q) adr##q = *(const int4*)(adjb + (q / 2) * 32 + (q % 2) * 4);
    FOR8(ADR_L0)

#define ACC_D(n) f32x4 accP##n = {0.f, 0.f, 0.f, 0.f}; f32x4 accN##n = {0.f, 0.f, 0.f, 0.f};
    FOR8(ACC_D)
    f32x4 acc8P = {0.f, 0.f, 0.f, 0.f};   // row-sum accumulators (ones-MFMA)
    f32x4 acc8N = {0.f, 0.f, 0.f, 0.f};
    bf16x8 ones;
    #pragma unroll
    for (int z = 0; z < 8; ++z) ones[z] = (short)0x3F80;   // bf16 1.0
    const int kg16 = kg * 16;

    __syncthreads();   // vpk/zpk LDS ready

#define STG_WR(v) *(int4*)((char*)tb + ldo##v) = stg##v;
#define STG_LN(v) stg##v = *(const int4*)(gsrc##v + so);
#define ADR_LN(q) adr##q = *(const int4*)(adjb + so + (q / 2) * 32 + (q % 2) * 4);
    // pos/neg fragment words for j-pair: select v (pos regime) or z (neg), masked by adj
#define PAIR(idx, av0, av1, vw, zw) { \
    const unsigned vw_ = (unsigned)(vw), zw_ = (unsigned)(zw); \
    const unsigned vh_ = vw_ & 0xFFFF0000u; \
    const float v0f = __uint_as_float(vw_ << 16); \
    const float v1f = __uint_as_float(vh_); \
    const bool m0 = (av0) > 0, m1 = (av1) > 0; \
    const bool b0 = v0f > thr, b1 = v1f > thr; \
    pw[idx] = (int)(((m0 && b0) ? (vw_ & 0xFFFFu) : 0u) | ((m1 && b1) ? vh_ : 0u)); \
    nw[idx] = (int)(((m0 && !b0) ? (zw_ & 0xFFFFu) : 0u) | ((m1 && !b1) ? (zw_ & 0xFFFF0000u) : 0u)); }
#define P8S(AFP, AFN, A0, A1, voff) { \
    int4 VP = *(const int4*)&vpk_lds[(voff)]; \
    int4 ZP = *(const int4*)&zpk_lds[(voff)]; \
    int pw[4], nw[4]; \
    PAIR(0, A0.x, A0.y, VP.x, ZP.x) \
    PAIR(1, A0.z, A0.w, VP.y, ZP.y) \
    PAIR(2, A1.x, A1.y, VP.z, ZP.z) \
    PAIR(3, A1.z, A1.w, VP.w, ZP.w) \
    int4 pi = {pw[0], pw[1], pw[2], pw[3]}; \
    int4 ni = {nw[0], nw[1], nw[2], nw[3]}; \
    AFP = __builtin_bit_cast(bf16x8, pi); \
    AFN = __builtin_bit_cast(bf16x8, ni); }
#define MFMA_ROW2(n) { const int c_ = n * 16 + row; \
    const int off_ = c_ * 256 + ((KB ^ ((c_ & 7) << 4))); \
    bf16x8 bv_ = *(const bf16x8*)((const char*)tb + off_); \
    accP##n = __builtin_amdgcn_mfma_f32_16x16x32_bf16(AP, bv_, accP##n, 0, 0, 0); \
    accN##n = __builtin_amdgcn_mfma_f32_16x16x32_bf16(AN, bv_, accN##n, 0, 0, 0); }
#define MFMA_KC2(afp, afn, kcl) { const bf16x8 AP = afp, AN = afn; const int KB = kcl * 64 + kg16; FOR8(MFMA_ROW2) \
    acc8P = __builtin_amdgcn_mfma_f32_16x16x32_bf16(AP, ones, acc8P, 0, 0, 0); \
    acc8N = __builtin_amdgcn_mfma_f32_16x16x32_bf16(AN, ones, acc8N, 0, 0, 0); }

    for (int s = 0; s < NST_; ++s) {
        unsigned short* tb = tile[s & 1];
        // A: fragments via compare+select (adj arrived a full step ago); no exp, no cvt
        bf16x8 afP0, afP1, afP2, afP3, afN0, afN1, afN2, afN3;
        {
            const int off = s * BKJ + kg8;
            P8S(afP0, afN0, adr0, adr1, off)
            P8S(afP1, afN1, adr2, adr3, off + 32)
            P8S(afP2, afN2, adr4, adr5, off + 64)
            P8S(afP3, afN3, adr6, adr7, off + 96)
        }
        // B: issue next adj loads (full-step lead covers HBM latency)
        if (s + 1 < NST_) {
            const size_t so = (size_t)(s + 1) * BKJ;
            FOR8(ADR_LN)
        }
        // C: write staged WhT tile (swizzled b128 writes)
        FOR8(STG_WR)
        // D: issue next WhT stage loads (L2-fast)
        if (s + 1 < NST_) {
            const size_t so = (size_t)(s + 1) * BKJ;
            FOR8(STG_LN)
        }
        // E: lgkm-only barrier — keep global prefetches in flight
        __builtin_amdgcn_sched_barrier(0);
        asm volatile("s_waitcnt lgkmcnt(0)" ::: "memory");
        __builtin_amdgcn_s_barrier();
        __builtin_amdgcn_sched_barrier(0);
        // F: MFMA 4 k-chunks x 8 col-tiles x {pos,neg} (+2 ones row-sums)
        MFMA_KC2(afP0, afN0, 0) MFMA_KC2(afP1, afN1, 1)
        MFMA_KC2(afP2, afN2, 2) MFMA_KC2(afP3, afN3, 3)
    }

    // per-output-row factors: row q of this lane's slots is iw+kg*4+q; u,w live at lane (kg*4+q)
    float uq[4], wq[4];
    #pragma unroll
    for (int r = 0; r < 4; ++r) {
        uq[r] = __shfl(uu, kg * 4 + r);
        wq[r] = __shfl(ww, kg * 4 + r);
    }
    float den[4];
    #pragma unroll
    for (int r = 0; r < 4; ++r) den[r] = uq[r] * acc8P[r] + wq[r] * acc8N[r];

    if (FINAL) {
#define FN_ROW(n) { size_t ob = (size_t)(iw + kg * 4) * FOUT + n * 16 + row; \
    _Pragma("unroll") for (int r = 0; r < 4; ++r) { \
        float o = (uq[r] * accP##n[r] + wq[r] * accN##n[r]) / den[r]; \
        out[ob + (size_t)r * FOUT] = (o > 0.f) ? o : expm1f(o); } }
        FOR8(FN_ROW)
    } else {
        if (row == 0) {
            #pragma unroll
            for (int q = 0; q < 4; ++q)
                lsum[(size_t)js * NN + iw + kg * 4 + q] = den[q];
        }
#define ST_ROW(n) { size_t ob = ((size_t)js * NN + iw + kg * 4) * FOUT + n * 16 + row; \
    _Pragma("unroll") for (int r = 0; r < 4; ++r) \
        Opart[ob + (size_t)r * FOUT] = uq[r] * accP##n[r] + wq[r] * accN##n[r]; }
        FOR8(ST_ROW)
    }
}

// ---------------- K3: merge j-splits (plain sums), divide, ELU ----------------
__global__ __launch_bounds__(256) void gat_k3(
    const float* __restrict__ lsum, const float* __restrict__ Opart,
    float* __restrict__ out)
{
    const int t = threadIdx.x;
    const int i = (int)blockIdx.x * 2 + (t >> 7);
    const int f = t & 127;
    float den = 0.f, num = 0.f;
    const size_t SP = (size_t)NN * FOUT;
    size_t base = (size_t)i * FOUT + f;
    #pragma unroll
    for (int k = 0; k < JSPLIT; ++k) {
        den += lsum[(size_t)k * NN + i];
        num += Opart[(size_t)k * SP + base];
    }
    float o = num / den;
    out[base] = (o > 0.f) ? o : expm1f(o);   // ELU, alpha=1
}

extern "C" void kernel_launch(void* const* d_in, const int* in_sizes, int n_in,
                              void* d_out, int out_size, void* d_ws, size_t ws_size,
                              hipStream_t stream) {
    const float* h  = (const float*)d_in[0];
    const int*  adj = (const int*)d_in[1];
    const float* W  = (const float*)d_in[2];
    const float* a  = (const float*)d_in[3];
    float* out = (float*)d_out;
    char* ws = (char*)d_ws;
    // ws: WhT 2MB | si 32KB | sj 32KB | sjmax 256B | vpk 16KB | zpk 16KB | lsum 128KB | Opart 16MB
    unsigned short* WhT = (unsigned short*)ws;
    float* si     = (float*)(ws + 2097152);
    float* sj     = (float*)(ws + 2129920);
    float* sjmax  = (float*)(ws + 2162688);
    unsigned short* vpk = (unsigned short*)(ws + 2162944);
    unsigned short* zpk = (unsigned short*)(ws + 2179328);
    float* lsum   = (float*)(ws + 2195712);
    float* Opart  = (float*)(ws + 2326784);

    gat_k1<<<256, 256, 0, stream>>>(h, W, a, WhT, si, sj);
    gat_k1v<<<1, 256, 0, stream>>>(sj, sjmax, vpk, zpk);
    gat_k2<JSPLIT, false><<<128 * JSPLIT, 256, 0, stream>>>(adj, WhT, si, vpk, zpk, sjmax, lsum, Opart, out);
    gat_k3<<<4096, 256, 0, stream>>>(lsum, Opart, out);
}